// Round 1
// baseline (1221.239 us; speedup 1.0000x reference)
//
#include <hip/hip_runtime.h>

typedef __bf16 bf16;
using bf16x8 = __attribute__((ext_vector_type(8))) __bf16;
using bf16x4 = __attribute__((ext_vector_type(4))) __bf16;
using f32x4  = __attribute__((ext_vector_type(4))) float;
using u32x4  = __attribute__((ext_vector_type(4))) unsigned int;

#define DEV __device__ __forceinline__

DEV float gelu_f(float x){ return 0.5f*x*(1.0f+erff(x*0.7071067811865475f)); }
DEV float sigm_f(float x){ return 1.0f/(1.0f+expf(-x)); }

// ---------------------------------------------------------------------------
// Tiled bf16 MFMA GEMM:  C[M,N] = A[M,K] @ B^T[N,K]^T   (B given transposed, N x K)
// 128x128 tile, BK=64, 256 threads (4 waves, 2x2), 16x16x32 MFMA,
// XOR-swizzled LDS (G4 fix) so ds_read_b128 is conflict-free.
// ---------------------------------------------------------------------------
enum { EPI_ADJ=0, EPI_BF16=1, EPI_GELU_BIAS=2, EPI_XUPD=3, EPI_BIAS_F32=4, EPI_F32=5 };

template<int EPI>
__global__ __launch_bounds__(256, 2)
void gemm_bt(const bf16* __restrict__ A, const bf16* __restrict__ B,
             int M, int N, int K, void* __restrict__ Cout, int ldc,
             const float* __restrict__ bias, const float* __restrict__ scal, int sidx,
             float* __restrict__ xu0, float* __restrict__ xu1)
{
    const int nb = N >> 7;
    const int bx = blockIdx.x % nb;          // N tile
    const int by = blockIdx.x / nb;          // M tile
    const int tid  = threadIdx.x;
    const int lane = tid & 63;
    const int wid  = tid >> 6;
    const int wr = wid >> 1, wc = wid & 1;   // 2x2 wave grid, each wave 64x64

    __shared__ bf16 lA[128*64];
    __shared__ bf16 lB[128*64];

    f32x4 acc[4][4] = {};

    const int lda = K, ldb = K;
    const int srow = tid >> 3;               // 0..31
    const int skc  = tid & 7;                // 0..7  (16B chunk within 64-elem row)
    const long aoff = (long)(by*128 + srow) * lda + skc*8;
    const long boff = (long)(bx*128 + srow) * ldb + skc*8;
    const int swz = ((skc ^ (srow & 7)) << 3);
    int woff[4];
#pragma unroll
    for (int i=0;i<4;i++) woff[i] = (i*32 + srow)*64 + swz;

    const int fr = lane & 15, fq = lane >> 4;
    int aroff[4], broff[4];
#pragma unroll
    for (int mi=0;mi<4;mi++) aroff[mi] = (wr*64 + mi*16 + fr)*64;
#pragma unroll
    for (int ni=0;ni<4;ni++) broff[ni] = (wc*64 + ni*16 + fr)*64;

    for (int kt = 0; kt < K; kt += 64) {
        u32x4 ra[4], rb[4];
#pragma unroll
        for (int i=0;i<4;i++){
            ra[i] = *(const u32x4*)(A + aoff + (long)i*32*lda + kt);
            rb[i] = *(const u32x4*)(B + boff + (long)i*32*ldb + kt);
        }
        __syncthreads();
#pragma unroll
        for (int i=0;i<4;i++){
            *(u32x4*)&lA[woff[i]] = ra[i];
            *(u32x4*)&lB[woff[i]] = rb[i];
        }
        __syncthreads();
#pragma unroll
        for (int ks=0; ks<2; ks++){
            bf16x8 af[4], bfr[4];
            const int kg = ks*4 + fq;
            const int sa = ((kg ^ (fr & 7)) << 3);
#pragma unroll
            for (int mi=0;mi<4;mi++) af[mi]  = *(const bf16x8*)&lA[aroff[mi] + sa];
#pragma unroll
            for (int ni=0;ni<4;ni++) bfr[ni] = *(const bf16x8*)&lB[broff[ni] + sa];
#pragma unroll
            for (int mi=0;mi<4;mi++)
#pragma unroll
                for (int ni=0;ni<4;ni++)
                    acc[mi][ni] = __builtin_amdgcn_mfma_f32_16x16x32_bf16(
                        af[mi], bfr[ni], acc[mi][ni], 0, 0, 0);
        }
    }

    float thr = 0.f;
    if constexpr (EPI==EPI_ADJ) thr = scal[sidx];

#pragma unroll
    for (int mi=0;mi<4;mi++){
#pragma unroll
        for (int ni=0;ni<4;ni++){
            const int col = bx*128 + wc*64 + ni*16 + fr;
#pragma unroll
            for (int r=0;r<4;r++){
                const int row = by*128 + wr*64 + mi*16 + fq*4 + r;
                const float v = acc[mi][ni][r];
                const long ci = (long)row*ldc + col;
                if constexpr (EPI==EPI_ADJ)       ((bf16*)Cout)[ci] = (bf16)sigm_f(10.f*(v - thr));
                else if constexpr (EPI==EPI_BF16) ((bf16*)Cout)[ci] = (bf16)v;
                else if constexpr (EPI==EPI_GELU_BIAS) ((bf16*)Cout)[ci] = (bf16)gelu_f(v + bias[col]);
                else if constexpr (EPI==EPI_BIAS_F32)  ((float*)Cout)[ci] = v + bias[col];
                else if constexpr (EPI==EPI_F32)       ((float*)Cout)[ci] = v;
                else if constexpr (EPI==EPI_XUPD){
                    const float u = 0.2f*(v + bias[col]);
                    xu0[ci] += u;  xu1[ci] += u;
                }
            }
        }
    }
}

// ---------------------------------------------------------------------------
// small kernels
// ---------------------------------------------------------------------------
__global__ void prep_kernel(const float* __restrict__ cs,
                            const float* __restrict__ W1, const float* __restrict__ b1,
                            const float* __restrict__ W2, const float* __restrict__ b2,
                            float* __restrict__ thrs)
{
    __shared__ float cp[1024];
    __shared__ float part[8][32];
    __shared__ float h[32];
    const int tid = threadIdx.x;
    for (int j = tid; j < 1024; j += 256){
        float s = 0.f;
#pragma unroll
        for (int r = 0; r < 8; r++) s += cs[r*1024 + j];
        cp[j] = s * 0.125f;
    }
    __syncthreads();
    const int t = tid & 31, g = tid >> 5;
    float p = 0.f;
    for (int j = g*128; j < g*128+128; j++) p += cp[j] * W1[j*32 + t];
    part[g][t] = p;
    __syncthreads();
    if (tid < 32){
        float s = b1[tid];
#pragma unroll
        for (int q=0;q<8;q++) s += part[q][tid];
        h[tid] = gelu_f(s);
    }
    __syncthreads();
    if (tid < 4){
        float z = b2[tid];
        for (int k=0;k<32;k++) z += h[k]*W2[k*4 + tid];
        thrs[tid] = sigm_f(z);
    }
    if (tid == 4) thrs[4] = 0.5f;   // betti threshold
}

__global__ void embed_kernel(const int* __restrict__ tok, const float* __restrict__ emb,
                             const float* __restrict__ pos, float* __restrict__ x)
{
    const long i = (long)blockIdx.x*256 + threadIdx.x;  // f32x4 index, 1,048,576 total
    const int  d4 = i & 255;
    const long bt = i >> 8;            // 0..4095
    const int  t  = (int)(bt & 2047);
    const int  token = tok[bt];
    f32x4 e = *(const f32x4*)(emb + (long)token*1024 + d4*4);
    f32x4 p = *(const f32x4*)(pos + (long)t*1024 + d4*4);
    *(f32x4*)(x + i*4) = e + p;
}

__global__ void transpose_f2b(const float* __restrict__ in, int ldin,
                              bf16* __restrict__ out, int ldout, int R, int C)
{
    __shared__ float tile[32][33];
    const int nbx = C >> 5;
    const int bx = blockIdx.x % nbx, by = blockIdx.x / nbx;
    const int tx = threadIdx.x & 31, ty = threadIdx.x >> 5; // 32x8
#pragma unroll
    for (int i=0;i<32;i+=8)
        tile[ty+i][tx] = in[(long)(by*32+ty+i)*ldin + bx*32+tx];
    __syncthreads();
#pragma unroll
    for (int i=0;i<32;i+=8)
        out[(long)(bx*32+ty+i)*ldout + by*32+tx] = (bf16)tile[tx][ty+i];
}

__global__ void rownorm_kernel(const float* __restrict__ x, bf16* __restrict__ xn,
                               bf16* __restrict__ x0b, int ld0)
{
    const long t = blockIdx.x; const int tid = threadIdx.x;
    f32x4 v = *(const f32x4*)(x + t*1024 + tid*4);
    float s = v.x*v.x + v.y*v.y + v.z*v.z + v.w*v.w;
#pragma unroll
    for (int o=32;o>0;o>>=1) s += __shfl_down(s, o);
    __shared__ float red[4];
    if ((tid&63)==0) red[tid>>6] = s;
    __syncthreads();
    const float tot = red[0]+red[1]+red[2]+red[3];
    const float inv = 1.0f / fmaxf(sqrtf(tot), 1e-12f);
    bf16x4 a, b;
    a[0]=(bf16)(v.x*inv); a[1]=(bf16)(v.y*inv); a[2]=(bf16)(v.z*inv); a[3]=(bf16)(v.w*inv);
    b[0]=(bf16)v.x; b[1]=(bf16)v.y; b[2]=(bf16)v.z; b[3]=(bf16)v.w;
    *(bf16x4*)(xn  + t*1024 + tid*4) = a;
    *(bf16x4*)(x0b + t*ld0  + tid*4) = b;
}

__global__ void degree_kernel(const bf16* __restrict__ adj, float* __restrict__ deg)
{
    const long t = blockIdx.x; const int tid = threadIdx.x;
    bf16x8 v = *(const bf16x8*)(adj + t*2048 + tid*8);
    float s = 0.f;
#pragma unroll
    for (int j=0;j<8;j++) s += (float)v[j];
#pragma unroll
    for (int o=32;o>0;o>>=1) s += __shfl_down(s, o);
    __shared__ float red[4];
    if ((tid&63)==0) red[tid>>6] = s;
    __syncthreads();
    if (tid==0) deg[t] = red[0]+red[1]+red[2]+red[3];
}

__global__ void betti_kernel(const float* __restrict__ deg, float* __restrict__ betti)
{
    const int tid = threadIdx.x;
    float s = 0.f, c = 0.f;
#pragma unroll
    for (int i=0;i<8;i++){
        const float d = deg[tid*8 + i];
        s += d;  c += (d < 0.5f) ? 1.f : 0.f;
    }
#pragma unroll
    for (int o=32;o>0;o>>=1){ s += __shfl_down(s,o); c += __shfl_down(c,o); }
    __shared__ float ss[4], cc[4];
    if ((tid&63)==0){ ss[tid>>6]=s; cc[tid>>6]=c; }
    __syncthreads();
    if (tid==0){
        const float S = ss[0]+ss[1]+ss[2]+ss[3];
        const float C = cc[0]+cc[1]+cc[2]+cc[3];
        const float ne = 0.5f*S;
        const float b1 = ne - 2048.f + C + 1.f;
        betti[0] = C;
        betti[1] = b1 > 0.f ? b1 : 0.f;
    }
}

// b1eff[j] = int_b1[j] + beta0*int_W1[1024][j] + beta1*int_W1[1025][j]
__global__ void b1eff_kernel(const float* __restrict__ ib1, const float* __restrict__ iW1,
                             const float* __restrict__ betti, float* __restrict__ out)
{
    const int j = blockIdx.x*256 + threadIdx.x;
    out[j] = ib1[j] + betti[0]*iW1[(long)1024*2048 + j] + betti[1]*iW1[(long)1025*2048 + j];
}

__global__ void f2b_kernel(const float* __restrict__ in, bf16* __restrict__ out)
{
    const long i = (long)blockIdx.x*256 + threadIdx.x;
    f32x4 a = *(const f32x4*)(in + i*8);
    f32x4 c = *(const f32x4*)(in + i*8 + 4);
    bf16x8 o;
    o[0]=(bf16)a.x; o[1]=(bf16)a.y; o[2]=(bf16)a.z; o[3]=(bf16)a.w;
    o[4]=(bf16)c.x; o[5]=(bf16)c.y; o[6]=(bf16)c.z; o[7]=(bf16)c.w;
    *(bf16x8*)(out + i*8) = o;
}

__global__ void ln_kernel(const float* __restrict__ y, const float* __restrict__ g,
                          const float* __restrict__ b, bf16* __restrict__ out)
{
    const long t = blockIdx.x; const int tid = threadIdx.x;
    f32x4 v = *(const f32x4*)(y + t*1024 + tid*4);
    float s  = v.x+v.y+v.z+v.w;
    float s2 = v.x*v.x+v.y*v.y+v.z*v.z+v.w*v.w;
#pragma unroll
    for (int o=32;o>0;o>>=1){ s += __shfl_down(s,o); s2 += __shfl_down(s2,o); }
    __shared__ float ss[4], qq[4];
    if ((tid&63)==0){ ss[tid>>6]=s; qq[tid>>6]=s2; }
    __syncthreads();
    const float S = ss[0]+ss[1]+ss[2]+ss[3], Q = qq[0]+qq[1]+qq[2]+qq[3];
    const float mu  = S * (1.f/1024.f);
    const float var = Q * (1.f/1024.f) - mu*mu;
    const float inv = rsqrtf(var + 1e-5f);
    f32x4 gv = *(const f32x4*)(g + tid*4);
    f32x4 bv = *(const f32x4*)(b + tid*4);
    bf16x4 o;
    o[0] = (bf16)((v.x - mu)*inv*gv.x + bv.x);
    o[1] = (bf16)((v.y - mu)*inv*gv.y + bv.y);
    o[2] = (bf16)((v.z - mu)*inv*gv.z + bv.z);
    o[3] = (bf16)((v.w - mu)*inv*gv.w + bv.w);
    *(bf16x4*)(out + t*1024 + tid*4) = o;
}

// ---------------------------------------------------------------------------
extern "C" void kernel_launch(void* const* d_in, const int* in_sizes, int n_in,
                              void* d_out, int out_size, void* d_ws, size_t ws_size,
                              hipStream_t stream)
{
    const int*   tokens = (const int*)  d_in[0];
    const float* cstate = (const float*)d_in[1];
    const float* embedW = (const float*)d_in[2];
    const float* posW   = (const float*)d_in[3];
    const float* thrW1  = (const float*)d_in[8];
    const float* thrb1  = (const float*)d_in[9];
    const float* thrW2  = (const float*)d_in[10];
    const float* thrb2  = (const float*)d_in[11];
    const float* simpW1 = (const float*)d_in[12];
    const float* simpb1 = (const float*)d_in[13];
    const float* simpW2 = (const float*)d_in[14];
    const float* simpb2 = (const float*)d_in[15];
    const float* intW1  = (const float*)d_in[16];
    const float* intb1  = (const float*)d_in[17];
    const float* intW2  = (const float*)d_in[18];
    const float* intb2  = (const float*)d_in[19];
    const float* lng    = (const float*)d_in[20];
    const float* lnb    = (const float*)d_in[21];
    const float* headW  = (const float*)d_in[22];
    float* out = (float*)d_out;

    size_t off = 0;
    auto carve = [&](size_t bytes) -> void* {
        void* p = (char*)d_ws + off;
        off += (bytes + 255) & ~(size_t)255;
        return p;
    };
    float* x_f32   = (float*)carve(16777216);   // [2][2048][1024] f32
    bf16*  xn      = (bf16*) carve(4194304);    // [2048][1024]
    bf16*  x0T     = (bf16*) carve(4194304);    // [1024][2048]  (contiguous after xn)
    bf16*  comb    = (bf16*) carve(8388608);    // [2048][2048]
    bf16*  adj     = (bf16*) carve(8388608);    // [2048][2048]  (contiguous after comb)
    bf16*  h1      = (bf16*) carve(4194304);    // [2048][1024]
    bf16*  xb      = (bf16*) carve(8388608);    // [4096][1024]
    bf16*  w1T     = (bf16*) carve(16777216);   // [4][1024][2048]
    bf16*  w2T     = (bf16*) carve(8388608);    // [4][1024][1024]
    bf16*  i1T     = (bf16*) carve(4194304);    // [2048][1024]
    bf16*  i2T     = (bf16*) carve(4194304);    // [1024][2048]
    bf16*  hT      = (bf16*) carve(65536000);   // [32000][1024]
    float* degree  = (float*)carve(8192);
    float* b1eff   = (float*)carve(8192);
    float* thrs    = (float*)carve(64);
    float* betti   = (float*)carve(64);
    // aliases (lifetimes disjoint):
    bf16*  h2  = comb;     // [4096][2048] over comb+adj (dead after betti/degree)
    float* yv  = x_f32;    // [4096][1024] f32 (x_f32 dead after f2b)
    bf16*  xln = xn;       // [4096][1024] over xn+x0T (dead after betti sim GEMM)

    const dim3 blk(256);

    prep_kernel<<<1, blk, 0, stream>>>(cstate, thrW1, thrb1, thrW2, thrb2, thrs);
    embed_kernel<<<4096, blk, 0, stream>>>(tokens, embedW, posW, x_f32);

    // weight transposes (f32 -> bf16, N x K layout)
    for (int l=0;l<4;l++)
        transpose_f2b<<<(1024/32)*(2048/32), blk, 0, stream>>>(
            simpW1 + (long)l*2048*1024, 1024, w1T + (long)l*1024*2048, 2048, 2048, 1024);
    for (int l=0;l<4;l++)
        transpose_f2b<<<(1024/32)*(1024/32), blk, 0, stream>>>(
            simpW2 + (long)l*1024*1024, 1024, w2T + (long)l*1024*1024, 1024, 1024, 1024);
    transpose_f2b<<<(2048/32)*(1024/32), blk, 0, stream>>>(intW1, 2048, i1T, 1024, 1024, 2048);
    transpose_f2b<<<(1024/32)*(2048/32), blk, 0, stream>>>(intW2, 1024, i2T, 2048, 2048, 1024);
    transpose_f2b<<<(32000/32)*(1024/32), blk, 0, stream>>>(headW, 32000, hT, 1024, 1024, 32000);

    // simplex levels
    for (int l=0;l<4;l++){
        rownorm_kernel<<<2048, blk, 0, stream>>>(x_f32, xn, comb, 2048);
        transpose_f2b<<<(1024/32)*(2048/32), blk, 0, stream>>>(x_f32, 1024, x0T, 2048, 2048, 1024);
        gemm_bt<EPI_ADJ><<<(2048/128)*(2048/128), blk, 0, stream>>>(
            xn, xn, 2048, 2048, 1024, adj, 2048, nullptr, thrs, l, nullptr, nullptr);
        gemm_bt<EPI_BF16><<<(1024/128)*(2048/128), blk, 0, stream>>>(
            adj, x0T, 2048, 1024, 2048, comb + 1024, 2048, nullptr, nullptr, 0, nullptr, nullptr);
        gemm_bt<EPI_GELU_BIAS><<<(1024/128)*(2048/128), blk, 0, stream>>>(
            comb, w1T + (long)l*1024*2048, 2048, 1024, 2048, h1, 1024,
            simpb1 + l*1024, nullptr, 0, nullptr, nullptr);
        gemm_bt<EPI_XUPD><<<(1024/128)*(2048/128), blk, 0, stream>>>(
            h1, w2T + (long)l*1024*1024, 2048, 1024, 1024, nullptr, 1024,
            simpb2 + l*1024, nullptr, 0, x_f32, x_f32 + (long)2048*1024);
    }

    // betti pass
    rownorm_kernel<<<2048, blk, 0, stream>>>(x_f32, xn, comb, 2048);
    gemm_bt<EPI_ADJ><<<(2048/128)*(2048/128), blk, 0, stream>>>(
        xn, xn, 2048, 2048, 1024, adj, 2048, nullptr, thrs, 4, nullptr, nullptr);
    degree_kernel<<<2048, blk, 0, stream>>>(adj, degree);
    betti_kernel<<<1, blk, 0, stream>>>(degree, betti);
    b1eff_kernel<<<8, blk, 0, stream>>>(intb1, intW1, betti, b1eff);

    // integrate + LN + head
    f2b_kernel<<<2048, blk, 0, stream>>>(x_f32, xb);   // 4096x1024 -> bf16
    gemm_bt<EPI_GELU_BIAS><<<(2048/128)*(4096/128), blk, 0, stream>>>(
        xb, i1T, 4096, 2048, 1024, h2, 2048, b1eff, nullptr, 0, nullptr, nullptr);
    gemm_bt<EPI_BIAS_F32><<<(1024/128)*(4096/128), blk, 0, stream>>>(
        h2, i2T, 4096, 1024, 2048, yv, 1024, intb2, nullptr, 0, nullptr, nullptr);
    ln_kernel<<<4096, blk, 0, stream>>>(yv, lng, lnb, xln);
    gemm_bt<EPI_F32><<<(32000/128)*(4096/128), blk, 0, stream>>>(
        xln, hT, 4096, 32000, 1024, out, 32000, nullptr, nullptr, 0, nullptr, nullptr);
}